// Round 2
// baseline (192.900 us; speedup 1.0000x reference)
//
#include <hip/hip_runtime.h>
#include <hip/hip_bf16.h>

#define N_SRC 50000
#define N_DST 50000
#define N_EDGES 600000
#define IN_FEAT 128
#define OUT_FEAT 128
#define CAP 64                          // per-dst bucket capacity (Poisson(12), P(deg>64)~1e-30)

typedef __attribute__((ext_vector_type(8))) short short8;   // 8 bf16 = 4 VGPRs
typedef __attribute__((ext_vector_type(4))) float float4v;  // MFMA C/D
typedef __attribute__((ext_vector_type(4))) float f32x4;
typedef __attribute__((ext_vector_type(4))) unsigned short ushort4v;

#define FILL_BLOCKS ((N_EDGES + 255) / 256)   // 2344
#define HS4 (N_SRC * IN_FEAT / 4)             // 1,600,000 float4s per matrix
#define CVT_BLOCKS (HS4 / 256)                // 6250
#define W_BLOCKS 16                           // 4096 8-elem chunks / 256
#define K1_GRID (FILL_BLOCKS + 2 * CVT_BLOCKS + W_BLOCKS)

// ---------------------------------------------------------------------------
// K1 (split-grid fusion; fill FIRST so its atomic stream starts immediately):
//   [0, FILL)            bucket-fill: p=atomicAdd(deg[d]); permu[d*CAP+p]=src
//   [FILL, +2*CVT)       f32->bf16 convert h_s->hsb, h_d->hdb
//   [.., +16)            W f32 -> fragment-major bf16 wfrag
// Streaming cvt STORES are nontemporal so they don't evict partially-filled
// perm lines from L2 (round-1 WRITE_SIZE showed ~26 MB of perm thrash).
// h_s/h_d/W loads are plain (harness may leave them L2/L3-warm).
// ---------------------------------------------------------------------------
__global__ __launch_bounds__(256) void fill_cvt_kernel(
    const float* __restrict__ h_s, const float* __restrict__ h_d,
    const float* __restrict__ W,
    const int* __restrict__ src, const int* __restrict__ dst,
    int* __restrict__ deg, ushort* __restrict__ permu,
    ushort* __restrict__ hsb, ushort* __restrict__ hdb,
    ushort* __restrict__ wfrag)
{
    int bid = blockIdx.x;
    int tid = threadIdx.x;

    if (bid < FILL_BLOCKS) {
        int e = bid * 256 + tid;
        if (e < N_EDGES) {
            int s = __builtin_nontemporal_load(src + e);
            int d = __builtin_nontemporal_load(dst + e);
            int p = atomicAdd(&deg[d], 1);
            if (p < CAP) permu[(size_t)d * CAP + p] = (ushort)s;
        }
        return;
    }
    bid -= FILL_BLOCKS;

    if (bid < 2 * CVT_BLOCKS) {
        bool first = (bid < CVT_BLOCKS);
        const float* in = first ? h_s : h_d;
        ushort* outp    = first ? hsb : hdb;
        int idx = (first ? bid : bid - CVT_BLOCKS) * 256 + tid;
        f32x4 v = *((const f32x4*)in + idx);
        __hip_bfloat16 o[4];
        o[0] = __float2bfloat16(v.x);
        o[1] = __float2bfloat16(v.y);
        o[2] = __float2bfloat16(v.z);
        o[3] = __float2bfloat16(v.w);
        __builtin_nontemporal_store(*(ushort4v*)o, (ushort4v*)(outp + (size_t)idx * 4));
        return;
    }
    bid -= 2 * CVT_BLOCKS;

    // ---- W convert to fragment-major bf16 (exact layout the GEMM reads):
    // chunk c: f=c>>6 (=ks*8+nt), l=c&63; elem = W[nt*16+(l&15)][ks*32+(l>>4)*8 ..+8]
    int c = bid * 256 + tid;              // [0, 4096)
    int f  = c >> 6;
    int l  = c & 63;
    int ks = f >> 3;
    int nt = f & 7;
    int row = nt * 16 + (l & 15);
    int col = ks * 32 + (l >> 4) * 8;
    const float* wp = W + (size_t)row * 256 + col;
    f32x4 w0 = *(const f32x4*)wp;
    f32x4 w1 = *((const f32x4*)wp + 1);
    __hip_bfloat16 o[8];
    o[0] = __float2bfloat16(w0.x); o[1] = __float2bfloat16(w0.y);
    o[2] = __float2bfloat16(w0.z); o[3] = __float2bfloat16(w0.w);
    o[4] = __float2bfloat16(w1.x); o[5] = __float2bfloat16(w1.y);
    o[6] = __float2bfloat16(w1.z); o[7] = __float2bfloat16(w1.w);
    __builtin_nontemporal_store(*(short8*)o, (short8*)(wfrag + (size_t)c * 8));
}

// ---------------------------------------------------------------------------
// K2 (fused gather-mean + MFMA GEMM), 512 thr / 8 waves, 128 dst rows/block.
// Phase A: wave w gather-means rows [w*16, w*16+16) into LDS (bf16,
//          XOR-swizzled: byte ^= (row&7)<<4 to kill the 16-way bank conflict
//          of row-major [128][128] bf16 under ds_read_b128).
// Phase B: out[tile] = [hdb | sN] @ wfrag.T + b. Each wave: 16 rows x 128
//          cols (1 m-frag x 8 n-frags). W frags loaded straight from global
//          wfrag (64 KB, L2-hot) — no LDS staging, LDS stays 32 KB.
// ---------------------------------------------------------------------------
__global__ __launch_bounds__(512) void gather_gemm_kernel(
    const ushort* __restrict__ hsb, const int* __restrict__ deg,
    const ushort* __restrict__ permu, const ushort* __restrict__ hdb,
    const ushort* __restrict__ wfrag, const float* __restrict__ b,
    float* __restrict__ out)
{
    __shared__ ushort sN[128 * 128];   // 32 KB neighbor-mean tile (swizzled)

    int tid  = threadIdx.x;
    int wave = tid >> 6;
    int lane = tid & 63;
    int row0 = blockIdx.x * 128;

    // ---- Phase A: gather-mean 16 rows per wave ----
    for (int r = 0; r < 16; ++r) {
        int lrow = wave * 16 + r;
        int row  = row0 + lrow;
        float ax = 0.f, ay = 0.f;
        if (row < N_DST) {
            int dg  = deg[row];
            int dgr = (dg < CAP) ? dg : CAP;
            const ushort* prow = permu + (size_t)row * CAP;
            int s0 = (dgr > 0) ? (int)prow[0] : 0;
            for (int j = 0; j < dgr; j += 8) {
                ushort4 pa = *(const ushort4*)(prow + j);
                ushort4 pb = *(const ushort4*)(prow + j + 4);
                int t[8] = {pa.x, pa.y, pa.z, pa.w, pb.x, pb.y, pb.z, pb.w};
                int   s[8];
                float m[8];
#pragma unroll
                for (int q = 0; q < 8; ++q) {
                    bool ok = (j + q < dgr);
                    s[q] = ok ? t[q] : s0;
                    m[q] = ok ? 1.f : 0.f;
                }
                ushort2 u[8];
#pragma unroll
                for (int q = 0; q < 8; ++q)
                    u[q] = ((const ushort2*)(hsb + (size_t)s[q] * IN_FEAT))[lane];
#pragma unroll
                for (int q = 0; q < 8; ++q) {
                    ax += m[q] * __uint_as_float((unsigned)u[q].x << 16);
                    ay += m[q] * __uint_as_float((unsigned)u[q].y << 16);
                }
            }
            float inv = (dg > 0) ? (1.0f / (float)dg) : 0.0f;
            ax *= inv; ay *= inv;
        }
        __hip_bfloat16 ox = __float2bfloat16(ax);
        __hip_bfloat16 oy = __float2bfloat16(ay);
        unsigned byte = ((unsigned)(lrow * 256 + lane * 4)) ^ (((unsigned)lrow & 7u) << 4);
        *(ushort2*)((char*)sN + byte) = make_ushort2(*(ushort*)&ox, *(ushort*)&oy);
    }
    __syncthreads();

    // ---- Phase B: MFMA ----
    int lm = lane & 15;
    int lk = (lane >> 4) * 8;
    int lrowA = wave * 16 + lm;

    int ar = row0 + lrowA;  ar = (ar < N_DST) ? ar : (N_DST - 1);
    const ushort* ah = hdb + (size_t)ar * IN_FEAT + lk;

    float4v acc[8];
#pragma unroll
    for (int nt = 0; nt < 8; ++nt) acc[nt] = (float4v){0.f, 0.f, 0.f, 0.f};

#pragma unroll
    for (int ks = 0; ks < 8; ++ks) {
        int koff = (ks & 3) * 32;
        short8 af;
        if (ks < 4) {
            af = *(const short8*)(ah + koff);
        } else {
            unsigned byte = ((unsigned)(lrowA * 256 + (lk + koff) * 2))
                            ^ (((unsigned)lrowA & 7u) << 4);
            af = *(const short8*)((char*)sN + byte);
        }
#pragma unroll
        for (int nt = 0; nt < 8; ++nt) {
            short8 bf = *(const short8*)(wfrag + ((size_t)(ks * 8 + nt) * 64 + lane) * 8);
            acc[nt] = __builtin_amdgcn_mfma_f32_16x16x32_bf16(af, bf, acc[nt], 0, 0, 0);
        }
    }

    // ---- epilogue: C/D layout col=lane&15, row=(lane>>4)*4+reg ----
    int orow0 = row0 + wave * 16 + (lane >> 4) * 4;
#pragma unroll
    for (int nt = 0; nt < 8; ++nt) {
        int col = nt * 16 + lm;
        float bias = b[col];
#pragma unroll
        for (int r = 0; r < 4; ++r) {
            int o = orow0 + r;
            if (o < N_DST) out[(size_t)o * OUT_FEAT + col] = acc[nt][r] + bias;
        }
    }
}

extern "C" void kernel_launch(void* const* d_in, const int* in_sizes, int n_in,
                              void* d_out, int out_size, void* d_ws, size_t ws_size,
                              hipStream_t stream) {
    const float* h_s = (const float*)d_in[0];
    const float* h_d = (const float*)d_in[1];
    const int*   src = (const int*)d_in[2];
    const int*   dst = (const int*)d_in[3];
    const float* W   = (const float*)d_in[4];
    const float* b   = (const float*)d_in[5];
    float* out = (float*)d_out;

    // workspace layout (~32.3 MB), all 16-B aligned:
    //   deg    int[50000]            @ 0          (200,000 B)
    //   permu  ushort[50000*64]      @ 200,000    (6,400,000 B)
    //   hsb    ushort[50000*128]     @ 6,600,000  (12,800,000 B)
    //   hdb    ushort[50000*128]     @ 19,400,000 (12,800,000 B)
    //   wfrag  ushort[32768]         @ 32,200,000 (65,536 B)
    char* ws = (char*)d_ws;
    int*    deg    = (int*)ws;
    ushort* permu  = (ushort*)(ws + 200000);
    ushort* hsb    = (ushort*)(ws + 6600000);
    ushort* hdb    = (ushort*)(ws + 19400000);
    ushort* wfrag  = (ushort*)(ws + 32200000);

    hipMemsetAsync(deg, 0, N_DST * sizeof(int), stream);

    fill_cvt_kernel<<<K1_GRID, 256, 0, stream>>>(
        h_s, h_d, W, src, dst, deg, permu, hsb, hdb, wfrag);
    gather_gemm_kernel<<<(N_DST + 127) / 128, 512, 0, stream>>>(
        hsb, deg, permu, hdb, wfrag, b, out);
}

// Round 3
// 178.822 us; speedup vs baseline: 1.0787x; 1.0787x over previous
//
#include <hip/hip_runtime.h>
#include <hip/hip_bf16.h>

#define N_SRC 50000
#define N_DST 50000
#define N_EDGES 600000
#define IN_FEAT 128
#define OUT_FEAT 128
#define CAP 64                          // per-dst bucket capacity (Poisson(12), P(deg>64)~1e-30)

typedef __attribute__((ext_vector_type(8))) short short8;   // 8 bf16 = 4 VGPRs
typedef __attribute__((ext_vector_type(4))) float float4v;  // MFMA C/D
typedef __attribute__((ext_vector_type(4))) float f32x4;
typedef __attribute__((ext_vector_type(4))) unsigned short ushort4v;

#define FILL_BLOCKS ((N_EDGES + 255) / 256)   // 2344
#define HS4 (N_SRC * IN_FEAT / 4)             // 1,600,000 float4s per matrix
#define CVT_BLOCKS (HS4 / 256)                // 6250
#define W_BLOCKS 16                           // 4096 8-elem chunks / 256
#define K1_GRID (FILL_BLOCKS + 2 * CVT_BLOCKS + W_BLOCKS)

// ---------------------------------------------------------------------------
// K1 (split-grid fusion; fill FIRST so its atomic stream starts immediately):
//   [0, FILL)            bucket-fill: p=atomicAdd(deg[d]); permu[d*CAP+p]=src
//   [FILL, +2*CVT)       f32->bf16 convert h_s->hsb, h_d->hdb
//   [.., +16)            W f32 -> fragment-major bf16 wfrag
// ALL streaming loads AND stores are nontemporal: the only data that wants
// L2 residency is the partially-filled permu lines (1 line per dst, ~12
// 2-B stores each) — evictions between slot-stores are the WRITE_SIZE
// amplification seen in rounds 0/1 (58/48 MB vs ~32 dense).
// ---------------------------------------------------------------------------
__global__ __launch_bounds__(256) void fill_cvt_kernel(
    const float* __restrict__ h_s, const float* __restrict__ h_d,
    const float* __restrict__ W,
    const int* __restrict__ src, const int* __restrict__ dst,
    int* __restrict__ deg, ushort* __restrict__ permu,
    ushort* __restrict__ hsb, ushort* __restrict__ hdb,
    ushort* __restrict__ wfrag)
{
    int bid = blockIdx.x;
    int tid = threadIdx.x;

    if (bid < FILL_BLOCKS) {
        int e = bid * 256 + tid;
        if (e < N_EDGES) {
            int s = __builtin_nontemporal_load(src + e);
            int d = __builtin_nontemporal_load(dst + e);
            int p = atomicAdd(&deg[d], 1);
            if (p < CAP) permu[(size_t)d * CAP + p] = (ushort)s;
        }
        return;
    }
    bid -= FILL_BLOCKS;

    if (bid < 2 * CVT_BLOCKS) {
        bool first = (bid < CVT_BLOCKS);
        const float* in = first ? h_s : h_d;
        ushort* outp    = first ? hsb : hdb;
        int idx = (first ? bid : bid - CVT_BLOCKS) * 256 + tid;
        f32x4 v = __builtin_nontemporal_load((const f32x4*)in + idx);
        __hip_bfloat16 o[4];
        o[0] = __float2bfloat16(v.x);
        o[1] = __float2bfloat16(v.y);
        o[2] = __float2bfloat16(v.z);
        o[3] = __float2bfloat16(v.w);
        __builtin_nontemporal_store(*(ushort4v*)o, (ushort4v*)(outp + (size_t)idx * 4));
        return;
    }
    bid -= 2 * CVT_BLOCKS;

    // ---- W convert to fragment-major bf16 (exact layout the GEMM reads):
    // chunk c: f=c>>6 (=ks*8+nt), l=c&63; elem = W[nt*16+(l&15)][ks*32+(l>>4)*8 ..+8]
    int c = bid * 256 + tid;              // [0, 4096)
    int f  = c >> 6;
    int l  = c & 63;
    int ks = f >> 3;
    int nt = f & 7;
    int row = nt * 16 + (l & 15);
    int col = ks * 32 + (l >> 4) * 8;
    const float* wp = W + (size_t)row * 256 + col;
    f32x4 w0 = __builtin_nontemporal_load((const f32x4*)wp);
    f32x4 w1 = __builtin_nontemporal_load((const f32x4*)wp + 1);
    __hip_bfloat16 o[8];
    o[0] = __float2bfloat16(w0.x); o[1] = __float2bfloat16(w0.y);
    o[2] = __float2bfloat16(w0.z); o[3] = __float2bfloat16(w0.w);
    o[4] = __float2bfloat16(w1.x); o[5] = __float2bfloat16(w1.y);
    o[6] = __float2bfloat16(w1.z); o[7] = __float2bfloat16(w1.w);
    __builtin_nontemporal_store(*(short8*)o, (short8*)(wfrag + (size_t)c * 8));
}

// ---------------------------------------------------------------------------
// K2: gather-mean, one wave per dst row (12500 blocks -> max TLP; the
// round-2 fusion that cut this to 391 blocks regressed badly).
// deg~Poisson(12): issue the first 16 slots as ONE batch of independent
// loads (fully covers ~89% of rows in a single dependent round; unused
// slots masked to row 0 = broadcast L1 hit), rare tail loop for deg>16.
// neighb stores nontemporal to protect hsb's L2 residency.
// ---------------------------------------------------------------------------
__global__ __launch_bounds__(256) void gather_kernel(
    const ushort* __restrict__ hsb, const int* __restrict__ deg,
    const ushort* __restrict__ permu, ushort* __restrict__ neighb)
{
    int wave = threadIdx.x >> 6;
    int lane = threadIdx.x & 63;
    int row  = blockIdx.x * 4 + wave;
    if (row >= N_DST) return;

    int dg  = deg[row];
    int dgr = (dg < CAP) ? dg : CAP;
    const ushort* prow = permu + (size_t)row * CAP;

    float ax = 0.f, ay = 0.f;
    {
        ushort4 p0 = *(const ushort4*)(prow);
        ushort4 p1 = *(const ushort4*)(prow + 4);
        ushort4 p2 = *(const ushort4*)(prow + 8);
        ushort4 p3 = *(const ushort4*)(prow + 12);
        int t[16] = {p0.x, p0.y, p0.z, p0.w, p1.x, p1.y, p1.z, p1.w,
                     p2.x, p2.y, p2.z, p2.w, p3.x, p3.y, p3.z, p3.w};
        ushort2 u[16];
#pragma unroll
        for (int q = 0; q < 16; ++q) {
            int s = (q < dgr) ? t[q] : 0;
            u[q] = ((const ushort2*)(hsb + (size_t)s * IN_FEAT))[lane];
        }
#pragma unroll
        for (int q = 0; q < 16; ++q) {
            float m = (q < dgr) ? 1.f : 0.f;
            ax += m * __uint_as_float((unsigned)u[q].x << 16);
            ay += m * __uint_as_float((unsigned)u[q].y << 16);
        }
    }
    for (int j = 16; j < dgr; j += 8) {          // rare (P(deg>16)~11%)
        ushort4 pa = *(const ushort4*)(prow + j);
        ushort4 pb = *(const ushort4*)(prow + j + 4);
        int t[8] = {pa.x, pa.y, pa.z, pa.w, pb.x, pb.y, pb.z, pb.w};
        ushort2 u[8];
#pragma unroll
        for (int q = 0; q < 8; ++q) {
            int s = (j + q < dgr) ? t[q] : 0;
            u[q] = ((const ushort2*)(hsb + (size_t)s * IN_FEAT))[lane];
        }
#pragma unroll
        for (int q = 0; q < 8; ++q) {
            float m = (j + q < dgr) ? 1.f : 0.f;
            ax += m * __uint_as_float((unsigned)u[q].x << 16);
            ay += m * __uint_as_float((unsigned)u[q].y << 16);
        }
    }
    float inv = (dg > 0) ? (1.0f / (float)dg) : 0.0f;
    __hip_bfloat16 ox = __float2bfloat16(ax * inv);
    __hip_bfloat16 oy = __float2bfloat16(ay * inv);
    unsigned pk = (unsigned)*(ushort*)&ox | ((unsigned)*(ushort*)&oy << 16);
    __builtin_nontemporal_store(pk, (unsigned*)(neighb + (size_t)row * IN_FEAT) + lane);
}

// ---------------------------------------------------------------------------
// K3: MFMA bf16 GEMM, zero LDS, zero syncthreads, 64 rows/block:
//   out = [hdb | neighb] @ wfrag.T + b      (782 blocks x 4 waves)
// Each wave: 16 rows x 128 cols = 1 m-frag x 8 n-frags, 64 MFMAs.
// B-frags stream from the 64 KB L2-hot wfrag; A/out are single-use ->
// nontemporal, keeping wfrag resident.
// ---------------------------------------------------------------------------
__global__ __launch_bounds__(256) void gemm_mfma_kernel(
    const ushort* __restrict__ hdb, const ushort* __restrict__ neighb,
    const ushort* __restrict__ wfrag, const float* __restrict__ b,
    float* __restrict__ out)
{
    int tid  = threadIdx.x;
    int wave = tid >> 6;
    int lane = tid & 63;
    int lm   = lane & 15;
    int lq   = lane >> 4;

    int row0 = blockIdx.x * 64 + wave * 16;
    int ar   = row0 + lm;  ar = (ar < N_DST) ? ar : (N_DST - 1);
    const ushort* ah = hdb    + (size_t)ar * IN_FEAT + lq * 8;
    const ushort* an = neighb + (size_t)ar * IN_FEAT + lq * 8;

    float4v acc[8];
#pragma unroll
    for (int nt = 0; nt < 8; ++nt) acc[nt] = (float4v){0.f, 0.f, 0.f, 0.f};

#pragma unroll
    for (int ks = 0; ks < 8; ++ks) {
        int koff = (ks & 3) * 32;
        short8 af = (ks < 4)
            ? __builtin_nontemporal_load((const short8*)(ah + koff))
            : __builtin_nontemporal_load((const short8*)(an + koff));
#pragma unroll
        for (int nt = 0; nt < 8; ++nt) {
            short8 bf = *(const short8*)(wfrag + ((size_t)(ks * 8 + nt) * 64 + lane) * 8);
            acc[nt] = __builtin_amdgcn_mfma_f32_16x16x32_bf16(af, bf, acc[nt], 0, 0, 0);
        }
    }

    // ---- epilogue: C/D layout col=lane&15, row=(lane>>4)*4+reg ----
    int orow0 = row0 + lq * 4;
#pragma unroll
    for (int nt = 0; nt < 8; ++nt) {
        int col = nt * 16 + lm;
        float bias = b[col];
#pragma unroll
        for (int r = 0; r < 4; ++r) {
            int o = orow0 + r;
            if (o < N_DST)
                __builtin_nontemporal_store(acc[nt][r] + bias,
                                            out + (size_t)o * OUT_FEAT + col);
        }
    }
}

extern "C" void kernel_launch(void* const* d_in, const int* in_sizes, int n_in,
                              void* d_out, int out_size, void* d_ws, size_t ws_size,
                              hipStream_t stream) {
    const float* h_s = (const float*)d_in[0];
    const float* h_d = (const float*)d_in[1];
    const int*   src = (const int*)d_in[2];
    const int*   dst = (const int*)d_in[3];
    const float* W   = (const float*)d_in[4];
    const float* b   = (const float*)d_in[5];
    float* out = (float*)d_out;

    // workspace layout (~45 MB), all 16-B aligned:
    //   deg    int[50000]            @ 0          (200,000 B)
    //   permu  ushort[50000*64]      @ 200,000    (6,400,000 B)
    //   hsb    ushort[50000*128]     @ 6,600,000  (12,800,000 B)
    //   hdb    ushort[50000*128]     @ 19,400,000 (12,800,000 B)
    //   neighb ushort[50000*128]     @ 32,200,000 (12,800,000 B)
    //   wfrag  ushort[32768]         @ 45,000,000 (65,536 B)
    char* ws = (char*)d_ws;
    int*    deg    = (int*)ws;
    ushort* permu  = (ushort*)(ws + 200000);
    ushort* hsb    = (ushort*)(ws + 6600000);
    ushort* hdb    = (ushort*)(ws + 19400000);
    ushort* neighb = (ushort*)(ws + 32200000);
    ushort* wfrag  = (ushort*)(ws + 45000000);

    hipMemsetAsync(deg, 0, N_DST * sizeof(int), stream);

    fill_cvt_kernel<<<K1_GRID, 256, 0, stream>>>(
        h_s, h_d, W, src, dst, deg, permu, hsb, hdb, wfrag);
    gather_kernel<<<(N_DST + 3) / 4, 256, 0, stream>>>(
        hsb, deg, permu, neighb);
    gemm_mfma_kernel<<<(N_DST + 63) / 64, 256, 0, stream>>>(
        hdb, neighb, wfrag, b, out);
}